// Round 1
// 117.800 us; speedup vs baseline: 1.0281x; 1.0281x over previous
//
#include <hip/hip_runtime.h>
#include <math.h>

// MDN_module: B rows, each: h = relu(x@W1 + b1) [64], out = h@W2 + b2 [4]
// mu = out[0:2], lv = out[2:4]; Lyapunov rescale; rsample fx; grand-sum logp_y.
//
// R4 strategy (register-pressure / stall reduction on top of R3):
//  1. Only x is hoisted at entry; V(x) is computed in the prologue so x dies
//     before the epilogue.
//  2. y/eps loads are issued between MLP chunk 11 and 12: 4 chunks (~1800 cyc
//     of VALU) cover the ~900-cyc HBM latency, but the +32 VGPRs are live for
//     only the loop tail instead of the whole kernel (R3 kept them live across
//     all 16 chunks and sat at the 128-VGPR launch_bounds limit).
//  3. Epilogue in v2f row-pair form (half the instructions, no hh-select).
//
//   W1 [2][64] row-major; W2 [64][4] row-major (float4/row); Wv [2][2]
//   d_out: fx (2B floats) then logp_y (1 float at index 2B)

typedef float v2f __attribute__((ext_vector_type(2)));

#define GRID 1024
#define BLOCK 256
#define NPAIR 4            // float4 row-pairs per thread -> 8 rows/thread (exact fit)
#define LOG_2PI 1.8378770664093453f

__device__ __forceinline__ float rcp_fast(float v) { return __builtin_amdgcn_rcpf(v); }
__device__ __forceinline__ v2f splat(float s) { v2f r; r.x = s; r.y = s; return r; }

// One 4-hidden-unit chunk of the MLP applied to all NPAIR row-pairs.
// Weight addresses are wave-uniform -> s_load; no LDS, no per-lane VMEM.
__device__ __forceinline__ void mlp_chunk(int c,
                                          const float* __restrict__ W1,
                                          const float* __restrict__ b1,
                                          const float* __restrict__ W2,
                                          const v2f (&X0)[NPAIR], const v2f (&X1)[NPAIR],
                                          v2f (&A0)[NPAIR], v2f (&A1)[NPAIR],
                                          v2f (&A2)[NPAIR], v2f (&A3)[NPAIR])
{
    const float4 wa = *reinterpret_cast<const float4*>(W1 + 4 * c);        // W1[0][4c..]
    const float4 wb = *reinterpret_cast<const float4*>(W1 + 64 + 4 * c);   // W1[1][4c..]
    const float4 bb = *reinterpret_cast<const float4*>(b1 + 4 * c);
    const float4 w2r[4] = {
        reinterpret_cast<const float4*>(W2)[4 * c + 0],
        reinterpret_cast<const float4*>(W2)[4 * c + 1],
        reinterpret_cast<const float4*>(W2)[4 * c + 2],
        reinterpret_cast<const float4*>(W2)[4 * c + 3],
    };
    #pragma unroll
    for (int j = 0; j < 4; ++j) {
        const v2f waj = splat((&wa.x)[j]);
        const v2f wbj = splat((&wb.x)[j]);
        const v2f bj  = splat((&bb.x)[j]);
        const v2f w20 = splat(w2r[j].x);
        const v2f w21 = splat(w2r[j].y);
        const v2f w22 = splat(w2r[j].z);
        const v2f w23 = splat(w2r[j].w);
        #pragma unroll
        for (int p = 0; p < NPAIR; ++p) {
            v2f h = __builtin_elementwise_fma(X1[p], wbj, bj);
            h = __builtin_elementwise_fma(X0[p], waj, h);
            h = __builtin_elementwise_max(h, splat(0.f));
            A0[p] = __builtin_elementwise_fma(h, w20, A0[p]);
            A1[p] = __builtin_elementwise_fma(h, w21, A1[p]);
            A2[p] = __builtin_elementwise_fma(h, w22, A2[p]);
            A3[p] = __builtin_elementwise_fma(h, w23, A3[p]);
        }
    }
}

__launch_bounds__(BLOCK, 4)
__global__ void mdn_kernel(const float* __restrict__ x,
                           const float* __restrict__ y,
                           const float* __restrict__ eps,
                           const float* __restrict__ W1,
                           const float* __restrict__ b1,
                           const float* __restrict__ W2,
                           const float* __restrict__ b2,
                           const float* __restrict__ Wv,
                           float* __restrict__ fx_out,
                           float* __restrict__ block_part,
                           int n_pairs)
{
    __shared__ float s_part[BLOCK / 64];

    const int t = threadIdx.x;
    const int T = GRID * BLOCK;
    const int g = blockIdx.x * BLOCK + t;

    // uniform scalars -> s_load
    const float b2_0 = b2[0], b2_1 = b2[1], b2_2 = b2[2], b2_3 = b2[3];
    const float wv00 = Wv[0], wv01 = Wv[1], wv10 = Wv[2], wv11 = Wv[3];

    v2f X0[NPAIR], X1[NPAIR], Vx[NPAIR];
    v2f A0[NPAIR], A1[NPAIR], A2[NPAIR], A3[NPAIR];

    // ---- prologue: x loads only ----
    #pragma unroll
    for (int p = 0; p < NPAIR; ++p) {
        const int rp = g + p * T;
        float4 xv = make_float4(0.f, 0.f, 0.f, 0.f);
        if (rp < n_pairs) xv = reinterpret_cast<const float4*>(x)[rp];
        X0[p].x = xv.x; X0[p].y = xv.z;   // rows 2rp, 2rp+1: x[0]
        X1[p].x = xv.y; X1[p].y = xv.w;   // rows 2rp, 2rp+1: x[1]
        A0[p] = splat(b2_0); A1[p] = splat(b2_1);
        A2[p] = splat(b2_2); A3[p] = splat(b2_3);
    }
    // V(x) now: x is then dead after the MLP loop (smaller epilogue live set).
    #pragma unroll
    for (int p = 0; p < NPAIR; ++p) {
        const v2f zx0 = __builtin_elementwise_fma(X0[p], splat(wv00), X1[p] * splat(wv10));
        const v2f zx1 = __builtin_elementwise_fma(X0[p], splat(wv01), X1[p] * splat(wv11));
        Vx[p] = __builtin_elementwise_fma(zx0, zx0,
                __builtin_elementwise_fma(zx1, zx1, splat(1e-3f)));
    }

    // ---- MLP chunks 0..11 (low register pressure: ~72 VGPRs live) ----
    #pragma unroll 2
    for (int c = 0; c < 12; ++c)
        mlp_chunk(c, W1, b1, W2, X0, X1, A0, A1, A2, A3);

    // ---- issue y/eps loads: 4 chunks of VALU cover the HBM latency ----
    float4 yv[NPAIR], ev[NPAIR];
    #pragma unroll
    for (int p = 0; p < NPAIR; ++p) {
        const int rp = g + p * T;
        yv[p] = make_float4(0.f, 0.f, 0.f, 0.f);
        ev[p] = make_float4(0.f, 0.f, 0.f, 0.f);
        if (rp < n_pairs) {
            yv[p] = reinterpret_cast<const float4*>(y)[rp];
            ev[p] = reinterpret_cast<const float4*>(eps)[rp];
        }
    }

    // ---- MLP chunks 12..15 ----
    #pragma unroll 2
    for (int c = 12; c < 16; ++c)
        mlp_chunk(c, W1, b1, W2, X0, X1, A0, A1, A2, A3);

    // ---- epilogue, v2f row-pair form (all operands in registers) ----
    v2f lsum = splat(0.f);
    #pragma unroll
    for (int p = 0; p < NPAIR; ++p) {
        const int rp = g + p * T;
        const v2f mu0 = A0[p], mu1 = A1[p], lv0 = A2[p], lv1 = A3[p];
        // V(mu)
        const v2f zm0 = __builtin_elementwise_fma(mu0, splat(wv00), mu1 * splat(wv10));
        const v2f zm1 = __builtin_elementwise_fma(mu0, splat(wv01), mu1 * splat(wv11));
        const v2f Vmu = __builtin_elementwise_fma(zm0, zm0,
                        __builtin_elementwise_fma(zm1, zm1, splat(1e-3f)));
        // scale = min(beta*Vx, Vmu)/Vmu
        const v2f num = __builtin_elementwise_min(splat(0.99f) * Vx[p], Vmu);
        v2f scale;
        scale.x = num.x * rcp_fast(Vmu.x);
        scale.y = num.y * rcp_fast(Vmu.y);
        const v2f ms0 = mu0 * scale, ms1 = mu1 * scale;
        // rsample: fx = ms + exp(lv/2)*eps ; inv-var = exp(-lv)
        v2f sd0, sd1, iv0, iv1;
        sd0.x = __expf(0.5f * lv0.x); sd0.y = __expf(0.5f * lv0.y);
        sd1.x = __expf(0.5f * lv1.x); sd1.y = __expf(0.5f * lv1.y);
        iv0.x = __expf(-lv0.x);       iv0.y = __expf(-lv0.y);
        iv1.x = __expf(-lv1.x);       iv1.y = __expf(-lv1.y);
        v2f e0; e0.x = ev[p].x; e0.y = ev[p].z;
        v2f e1; e1.x = ev[p].y; e1.y = ev[p].w;
        const v2f f0 = __builtin_elementwise_fma(sd0, e0, ms0);
        const v2f f1 = __builtin_elementwise_fma(sd1, e1, ms1);
        // -logp contribution
        v2f y0; y0.x = yv[p].x; y0.y = yv[p].z;
        v2f y1; y1.x = yv[p].y; y1.y = yv[p].w;
        const v2f d0 = y0 - ms0, d1 = y1 - ms1;
        const v2f q = __builtin_elementwise_fma(d0 * d0, iv0, (d1 * d1) * iv1);
        if (rp < n_pairs) {
            float4 fxv;
            fxv.x = f0.x; fxv.y = f1.x;   // row 2rp
            fxv.z = f0.y; fxv.w = f1.y;   // row 2rp+1
            reinterpret_cast<float4*>(fx_out)[rp] = fxv;
            lsum = lsum + __builtin_elementwise_fma(splat(0.5f), q + lv0 + lv1,
                                                    splat(LOG_2PI));
        }
    }
    float ls = lsum.x + lsum.y;

    // reduce: wave shuffle -> LDS -> one partial per block (no atomics)
    #pragma unroll
    for (int off = 32; off; off >>= 1) ls += __shfl_xor(ls, off, 64);
    if ((t & 63) == 0) s_part[t >> 6] = ls;
    __syncthreads();
    if (t == 0) {
        float bs = 0.f;
        #pragma unroll
        for (int w = 0; w < BLOCK / 64; ++w) bs += s_part[w];
        block_part[blockIdx.x] = bs;
    }
}

// Sum GRID per-block partials -> logp_out. One block of 256 threads.
__launch_bounds__(BLOCK, 1)
__global__ void mdn_reduce_kernel(const float* __restrict__ block_part,
                                  float* __restrict__ logp_out)
{
    __shared__ float s_part[BLOCK / 64];
    const int t = threadIdx.x;
    float s = 0.f;
    #pragma unroll
    for (int k = 0; k < GRID / BLOCK; ++k) s += block_part[t + k * BLOCK];
    #pragma unroll
    for (int off = 32; off; off >>= 1) s += __shfl_xor(s, off, 64);
    if ((t & 63) == 0) s_part[t >> 6] = s;
    __syncthreads();
    if (t == 0) {
        float bs = 0.f;
        #pragma unroll
        for (int w = 0; w < BLOCK / 64; ++w) bs += s_part[w];
        *logp_out = bs;
    }
}

extern "C" void kernel_launch(void* const* d_in, const int* in_sizes, int n_in,
                              void* d_out, int out_size, void* d_ws, size_t ws_size,
                              hipStream_t stream) {
    const float* x   = (const float*)d_in[0];
    const float* y   = (const float*)d_in[1];
    const float* eps = (const float*)d_in[2];
    const float* W1  = (const float*)d_in[3];
    const float* b1  = (const float*)d_in[4];
    const float* W2  = (const float*)d_in[5];
    const float* b2  = (const float*)d_in[6];
    const float* Wv  = (const float*)d_in[7];

    const int B = in_sizes[0] / 2;          // rows
    const int n_pairs = B / 2;              // float4 row-pairs
    float* fx_out     = (float*)d_out;
    float* logp_out   = fx_out + (size_t)2 * B;   // scalar at flat index 2B
    float* block_part = (float*)d_ws;             // GRID floats of scratch

    mdn_kernel<<<GRID, BLOCK, 0, stream>>>(x, y, eps, W1, b1, W2, b2, Wv,
                                           fx_out, block_part, n_pairs);
    mdn_reduce_kernel<<<1, BLOCK, 0, stream>>>(block_part, logp_out);
}

// Round 2
// 116.889 us; speedup vs baseline: 1.0361x; 1.0078x over previous
//
#include <hip/hip_runtime.h>
#include <math.h>

// MDN_module: B rows, each: h = relu(x@W1 + b1) [64], out = h@W2 + b2 [4]
// mu = out[0:2], lv = out[2:4]; Lyapunov rescale; rsample fx; grand-sum logp_y.
//
// R5 strategy (phase-overlap via occupancy, on top of R4):
//   Theory: at launch_bounds(256,4)/NPAIR=4 the whole chip is ONE lockstep
//   batch of waves -> x-burst, MLP, y/eps-burst, store-burst serialize
//   (~2.7 + 11 + 3.4 + 2.7 us ~= observed ~26 us vs ~12 us overlapped floor).
//   Fix: NPAIR=1, GRID=4096, launch_bounds(256,8): ~50 peak VGPRs fits the
//   64-VGPR cap for 8 waves/SIMD, 16 blocks/CU = 2 residency generations ->
//   loads/compute/stores overlap ACROSS waves instead of serializing.
//
//   W1 [2][64] row-major; W2 [64][4] row-major (float4/row); Wv [2][2]
//   d_out: fx (2B floats) then logp_y (1 float at index 2B)

typedef float v2f __attribute__((ext_vector_type(2)));

#define GRID 4096
#define BLOCK 256
#define LOG_2PI 1.8378770664093453f

__device__ __forceinline__ float rcp_fast(float v) { return __builtin_amdgcn_rcpf(v); }
__device__ __forceinline__ v2f splat(float s) { v2f r; r.x = s; r.y = s; return r; }

// One 4-hidden-unit chunk of the MLP applied to this thread's row-pair.
// Weight addresses are wave-uniform -> s_load; no LDS, no per-lane VMEM.
__device__ __forceinline__ void mlp_chunk(int c,
                                          const float* __restrict__ W1,
                                          const float* __restrict__ b1,
                                          const float* __restrict__ W2,
                                          v2f X0, v2f X1,
                                          v2f& A0, v2f& A1, v2f& A2, v2f& A3)
{
    const float4 wa = *reinterpret_cast<const float4*>(W1 + 4 * c);        // W1[0][4c..]
    const float4 wb = *reinterpret_cast<const float4*>(W1 + 64 + 4 * c);   // W1[1][4c..]
    const float4 bb = *reinterpret_cast<const float4*>(b1 + 4 * c);
    const float4 w2r[4] = {
        reinterpret_cast<const float4*>(W2)[4 * c + 0],
        reinterpret_cast<const float4*>(W2)[4 * c + 1],
        reinterpret_cast<const float4*>(W2)[4 * c + 2],
        reinterpret_cast<const float4*>(W2)[4 * c + 3],
    };
    #pragma unroll
    for (int j = 0; j < 4; ++j) {
        v2f h = __builtin_elementwise_fma(X1, splat((&wb.x)[j]), splat((&bb.x)[j]));
        h = __builtin_elementwise_fma(X0, splat((&wa.x)[j]), h);
        h = __builtin_elementwise_max(h, splat(0.f));
        A0 = __builtin_elementwise_fma(h, splat(w2r[j].x), A0);
        A1 = __builtin_elementwise_fma(h, splat(w2r[j].y), A1);
        A2 = __builtin_elementwise_fma(h, splat(w2r[j].z), A2);
        A3 = __builtin_elementwise_fma(h, splat(w2r[j].w), A3);
    }
}

__launch_bounds__(BLOCK, 8)
__global__ void mdn_kernel(const float* __restrict__ x,
                           const float* __restrict__ y,
                           const float* __restrict__ eps,
                           const float* __restrict__ W1,
                           const float* __restrict__ b1,
                           const float* __restrict__ W2,
                           const float* __restrict__ b2,
                           const float* __restrict__ Wv,
                           float* __restrict__ fx_out,
                           float* __restrict__ block_part,
                           int n_pairs)
{
    __shared__ float s_part[BLOCK / 64];

    const int t = threadIdx.x;
    const int g = blockIdx.x * BLOCK + t;   // this thread's row-pair index

    // uniform scalars -> s_load
    const float b2_0 = b2[0], b2_1 = b2[1], b2_2 = b2[2], b2_3 = b2[3];
    const float wv00 = Wv[0], wv01 = Wv[1], wv10 = Wv[2], wv11 = Wv[3];

    // ---- prologue: x load only ----
    float4 xv = make_float4(0.f, 0.f, 0.f, 0.f);
    if (g < n_pairs) xv = reinterpret_cast<const float4*>(x)[g];
    v2f X0, X1;
    X0.x = xv.x; X0.y = xv.z;   // rows 2g, 2g+1: x[0]
    X1.x = xv.y; X1.y = xv.w;   // rows 2g, 2g+1: x[1]
    v2f A0 = splat(b2_0), A1 = splat(b2_1), A2 = splat(b2_2), A3 = splat(b2_3);

    // V(x) now: x dies with the MLP loop (small epilogue live set).
    const v2f zx0 = __builtin_elementwise_fma(X0, splat(wv00), X1 * splat(wv10));
    const v2f zx1 = __builtin_elementwise_fma(X0, splat(wv01), X1 * splat(wv11));
    const v2f Vx  = __builtin_elementwise_fma(zx0, zx0,
                    __builtin_elementwise_fma(zx1, zx1, splat(1e-3f)));

    // ---- MLP chunks 0..11 ----
    #pragma unroll 2
    for (int c = 0; c < 12; ++c)
        mlp_chunk(c, W1, b1, W2, X0, X1, A0, A1, A2, A3);

    // ---- issue y/eps loads: tail chunks + inter-wave overlap cover latency ----
    float4 yv = make_float4(0.f, 0.f, 0.f, 0.f);
    float4 ev = make_float4(0.f, 0.f, 0.f, 0.f);
    if (g < n_pairs) {
        yv = reinterpret_cast<const float4*>(y)[g];
        ev = reinterpret_cast<const float4*>(eps)[g];
    }

    // ---- MLP chunks 12..15 ----
    #pragma unroll 2
    for (int c = 12; c < 16; ++c)
        mlp_chunk(c, W1, b1, W2, X0, X1, A0, A1, A2, A3);

    // ---- epilogue, v2f row-pair form (all operands in registers) ----
    const v2f mu0 = A0, mu1 = A1, lv0 = A2, lv1 = A3;
    // V(mu)
    const v2f zm0 = __builtin_elementwise_fma(mu0, splat(wv00), mu1 * splat(wv10));
    const v2f zm1 = __builtin_elementwise_fma(mu0, splat(wv01), mu1 * splat(wv11));
    const v2f Vmu = __builtin_elementwise_fma(zm0, zm0,
                    __builtin_elementwise_fma(zm1, zm1, splat(1e-3f)));
    // scale = min(beta*Vx, Vmu)/Vmu
    const v2f num = __builtin_elementwise_min(splat(0.99f) * Vx, Vmu);
    v2f scale;
    scale.x = num.x * rcp_fast(Vmu.x);
    scale.y = num.y * rcp_fast(Vmu.y);
    const v2f ms0 = mu0 * scale, ms1 = mu1 * scale;
    // rsample: fx = ms + exp(lv/2)*eps ; inv-var = exp(-lv)
    v2f sd0, sd1, iv0, iv1;
    sd0.x = __expf(0.5f * lv0.x); sd0.y = __expf(0.5f * lv0.y);
    sd1.x = __expf(0.5f * lv1.x); sd1.y = __expf(0.5f * lv1.y);
    iv0.x = __expf(-lv0.x);       iv0.y = __expf(-lv0.y);
    iv1.x = __expf(-lv1.x);       iv1.y = __expf(-lv1.y);
    v2f e0; e0.x = ev.x; e0.y = ev.z;
    v2f e1; e1.x = ev.y; e1.y = ev.w;
    const v2f f0 = __builtin_elementwise_fma(sd0, e0, ms0);
    const v2f f1 = __builtin_elementwise_fma(sd1, e1, ms1);
    // -logp contribution
    v2f y0; y0.x = yv.x; y0.y = yv.z;
    v2f y1; y1.x = yv.y; y1.y = yv.w;
    const v2f d0 = y0 - ms0, d1 = y1 - ms1;
    const v2f q = __builtin_elementwise_fma(d0 * d0, iv0, (d1 * d1) * iv1);

    v2f lsum = splat(0.f);
    if (g < n_pairs) {
        float4 fxv;
        fxv.x = f0.x; fxv.y = f1.x;   // row 2g
        fxv.z = f0.y; fxv.w = f1.y;   // row 2g+1
        reinterpret_cast<float4*>(fx_out)[g] = fxv;
        lsum = __builtin_elementwise_fma(splat(0.5f), q + lv0 + lv1, splat(LOG_2PI));
    }
    float ls = lsum.x + lsum.y;

    // reduce: wave shuffle -> LDS -> one partial per block (no atomics)
    #pragma unroll
    for (int off = 32; off; off >>= 1) ls += __shfl_xor(ls, off, 64);
    if ((t & 63) == 0) s_part[t >> 6] = ls;
    __syncthreads();
    if (t == 0) {
        float bs = 0.f;
        #pragma unroll
        for (int w = 0; w < BLOCK / 64; ++w) bs += s_part[w];
        block_part[blockIdx.x] = bs;
    }
}

// Sum GRID per-block partials -> logp_out. One block of 256 threads.
__launch_bounds__(BLOCK, 1)
__global__ void mdn_reduce_kernel(const float* __restrict__ block_part,
                                  float* __restrict__ logp_out)
{
    __shared__ float s_part[BLOCK / 64];
    const int t = threadIdx.x;
    float s = 0.f;
    #pragma unroll
    for (int k = 0; k < GRID / BLOCK; ++k) s += block_part[t + k * BLOCK];
    #pragma unroll
    for (int off = 32; off; off >>= 1) s += __shfl_xor(s, off, 64);
    if ((t & 63) == 0) s_part[t >> 6] = s;
    __syncthreads();
    if (t == 0) {
        float bs = 0.f;
        #pragma unroll
        for (int w = 0; w < BLOCK / 64; ++w) bs += s_part[w];
        *logp_out = bs;
    }
}

extern "C" void kernel_launch(void* const* d_in, const int* in_sizes, int n_in,
                              void* d_out, int out_size, void* d_ws, size_t ws_size,
                              hipStream_t stream) {
    const float* x   = (const float*)d_in[0];
    const float* y   = (const float*)d_in[1];
    const float* eps = (const float*)d_in[2];
    const float* W1  = (const float*)d_in[3];
    const float* b1  = (const float*)d_in[4];
    const float* W2  = (const float*)d_in[5];
    const float* b2  = (const float*)d_in[6];
    const float* Wv  = (const float*)d_in[7];

    const int B = in_sizes[0] / 2;          // rows
    const int n_pairs = B / 2;              // float4 row-pairs
    float* fx_out     = (float*)d_out;
    float* logp_out   = fx_out + (size_t)2 * B;   // scalar at flat index 2B
    float* block_part = (float*)d_ws;             // GRID floats of scratch

    mdn_kernel<<<GRID, BLOCK, 0, stream>>>(x, y, eps, W1, b1, W2, b2, Wv,
                                           fx_out, block_part, n_pairs);
    mdn_reduce_kernel<<<1, BLOCK, 0, stream>>>(block_part, logp_out);
}